// Round 1
// baseline (282.532 us; speedup 1.0000x reference)
//
#include <hip/hip_runtime.h>

#define N_NODES 100000
#define N_EDGES 1600000
#define D 64
#define XROW 64                                   // ab row: 64 bf16 (x only)
#define WROW 128                                  // Wb row: [rel_W | root_W]
#define NPB 128                                   // nodes per bucket
#define NBUCK ((N_NODES + NPB - 1) / NPB)         // 782
#define CHUNK 8192                                // edges per partition block
#define NCHUNK ((N_EDGES + CHUNK - 1) / CHUNK)    // 196  (must be <= 256 CUs for co-residency)
#define ASTRIDE 72                                // a_sh row stride (bf16), 144 B: 16B-aligned

typedef __attribute__((ext_vector_type(8))) short bf16x8;
typedef __attribute__((ext_vector_type(4))) float f32x4;

__device__ __forceinline__ unsigned short f2bf(float f) {
    unsigned bits = __float_as_uint(f);
    bits += 0x7FFF + ((bits >> 16) & 1);          // RNE
    return (unsigned short)(bits >> 16);
}

// Device-scope grid barrier. Safe because grid (196) <= CU count (256) -> all
// blocks co-resident. bar[0]=arrive count, bar[1]=generation (memset each launch).
__device__ __forceinline__ void grid_bar(int* bar, int nblk) {
    __syncthreads();
    if (threadIdx.x == 0) {
        int g = __hip_atomic_load(bar + 1, __ATOMIC_RELAXED, __HIP_MEMORY_SCOPE_AGENT);
        __threadfence();                           // release: flush this block's stores (cross-XCD L2 wb)
        int a = __hip_atomic_fetch_add(bar, 1, __ATOMIC_ACQ_REL, __HIP_MEMORY_SCOPE_AGENT);
        if (a == nblk - 1) {
            __hip_atomic_store(bar, 0, __ATOMIC_RELAXED, __HIP_MEMORY_SCOPE_AGENT);
            __hip_atomic_fetch_add(bar + 1, 1, __ATOMIC_ACQ_REL, __HIP_MEMORY_SCOPE_AGENT);
        } else {
            while (__hip_atomic_load(bar + 1, __ATOMIC_RELAXED, __HIP_MEMORY_SCOPE_AGENT) == g)
                __builtin_amdgcn_s_sleep(8);
        }
        __threadfence();                           // acquire: invalidate L1/L2 before next phase reads
    }
    __syncthreads();
}

// ================================================================ persistent pre-processing
// Phase A: x->bf16 (ab), weights->bf16 (Wb)   [no deps]
// Phase B: bucket histogram                    -> bar
// Phase C: exclusive scan (block 0)            -> bar
// Phase D: partition edges into bucket runs    -> bar
// Phase E: per-bucket counting sort -> per-node CSR (off/deg/edge_src)
__global__ __launch_bounds__(1024) void pre_kernel(
    const float* __restrict__ x, const float* __restrict__ rel_W,
    const float* __restrict__ root_W, const int* __restrict__ row,
    const int* __restrict__ col,
    unsigned short* __restrict__ ab, unsigned short* __restrict__ Wb,
    int* __restrict__ bar, int* __restrict__ bucketTot,
    int* __restrict__ bucketBase, int* __restrict__ bucketCur,
    int* __restrict__ edges, int* __restrict__ edge_src,
    int* __restrict__ off, int* __restrict__ deg)
{
    __shared__ int shm[3 * NBUCK];
    const int tid  = threadIdx.x;
    const int gtid = blockIdx.x * 1024 + tid;
    const int nthr = NCHUNK * 1024;

    // ---------------- phase A: staging (grid-stride)
    for (int t = gtid; t < N_NODES * 8; t += nthr) {
        int nrow = t >> 3, g = t & 7;
        const float4* xf = (const float4*)(x + (size_t)nrow * D + g * 8);
        float4 a = xf[0], b = xf[1];
        unsigned short u[8];
        u[0] = f2bf(a.x); u[1] = f2bf(a.y); u[2] = f2bf(a.z); u[3] = f2bf(a.w);
        u[4] = f2bf(b.x); u[5] = f2bf(b.y); u[6] = f2bf(b.z); u[7] = f2bf(b.w);
        *reinterpret_cast<uint4*>(ab + (size_t)nrow * XROW + g * 8) =
            *reinterpret_cast<const uint4*>(u);
    }
    if (gtid < 1024) {
        int j = gtid >> 4, g = gtid & 15;
        const float* src = (g < 8) ? (rel_W + j * 64 + g * 8) : (root_W + j * 64 + (g - 8) * 8);
        unsigned short u[8];
        #pragma unroll
        for (int i = 0; i < 8; ++i) u[i] = f2bf(src[i]);
        *reinterpret_cast<uint4*>(Wb + j * WROW + g * 8) = *reinterpret_cast<const uint4*>(u);
    }

    // ---------------- phase B: histogram (LDS-staged)
    for (int k = tid; k < NBUCK; k += 1024) shm[k] = 0;
    __syncthreads();
    {
        int base = blockIdx.x * CHUNK;
        #pragma unroll
        for (int it = 0; it < CHUNK / 1024; ++it) {
            int e = base + it * 1024 + tid;
            if (e < N_EDGES) atomicAdd(&shm[col[e] >> 7], 1);
        }
    }
    __syncthreads();
    for (int k = tid; k < NBUCK; k += 1024)
        if (shm[k]) atomicAdd(&bucketTot[k], shm[k]);

    grid_bar(bar, gridDim.x);

    // ---------------- phase C: exclusive scan of 782 totals (block 0 only)
    if (blockIdx.x == 0) {
        int v = (tid < NBUCK) ? bucketTot[tid] : 0;
        int lane = tid & 63, wave = tid >> 6;
        int s = v;
        #pragma unroll
        for (int o = 1; o < 64; o <<= 1) {
            int t = __shfl_up(s, o, 64);
            if (lane >= o) s += t;
        }
        if (lane == 63) shm[wave] = s;
        __syncthreads();
        if (wave == 0 && lane < 16) {
            int w = shm[lane];
            #pragma unroll
            for (int o = 1; o < 16; o <<= 1) {
                int t = __shfl_up(w, o, 64);
                if (lane >= o) w += t;
            }
            shm[lane] = w;
        }
        __syncthreads();
        int excl = s - v + (wave ? shm[wave - 1] : 0);
        if (tid < NBUCK) { bucketBase[tid] = excl; bucketCur[tid] = excl; }
    }

    grid_bar(bar, gridDim.x);

    // ---------------- phase D: partition into bucketed runs
    {
        int* cnt = shm; int* runStart = shm + NBUCK; int* rank = shm + 2 * NBUCK;
        for (int k = tid; k < NBUCK; k += 1024) { cnt[k] = 0; rank[k] = 0; }
        __syncthreads();
        int base = blockIdx.x * CHUNK;
        #pragma unroll
        for (int it = 0; it < CHUNK / 1024; ++it) {
            int e = base + it * 1024 + tid;
            if (e < N_EDGES) atomicAdd(&cnt[col[e] >> 7], 1);
        }
        __syncthreads();
        for (int k = tid; k < NBUCK; k += 1024) {
            int c = cnt[k];
            runStart[k] = c ? atomicAdd(&bucketCur[k], c) : 0;
        }
        __syncthreads();
        #pragma unroll
        for (int it = 0; it < CHUNK / 1024; ++it) {
            int e = base + it * 1024 + tid;
            if (e < N_EDGES) {
                int d = col[e];
                int b = d >> 7;
                int r = atomicAdd(&rank[b], 1);
                edges[runStart[b] + r] = ((d & (NPB - 1)) << 17) | row[e];  // src < 2^17
            }
        }
    }

    grid_bar(bar, gridDim.x);

    // ---------------- phase E: per-bucket counting sort -> per-node CSR
    {
        int* cnt = shm; int* offL = shm + NPB; int* cur = shm + 2 * NPB;
        for (int b = blockIdx.x; b < NBUCK; b += NCHUNK) {
            int base = bucketBase[b];
            int tot  = bucketTot[b];
            if (tid < NPB) cnt[tid] = 0;
            __syncthreads();
            for (int i = base + tid; i < base + tot; i += 1024)
                atomicAdd(&cnt[edges[i] >> 17], 1);
            __syncthreads();
            if (tid < 64) {
                int v0 = cnt[2 * tid], v1 = cnt[2 * tid + 1];
                int s = v0 + v1;
                #pragma unroll
                for (int o = 1; o < 64; o <<= 1) {
                    int t = __shfl_up(s, o, 64);
                    if (tid >= o) s += t;
                }
                offL[2 * tid]     = s - v1 - v0;
                offL[2 * tid + 1] = s - v1;
                cur[2 * tid]      = s - v1 - v0;
                cur[2 * tid + 1]  = s - v1;
            }
            __syncthreads();
            for (int i = base + tid; i < base + tot; i += 1024) {
                int p = edges[i];
                int l = p >> 17;
                int r = atomicAdd(&cur[l], 1);
                edge_src[base + r] = p & 0x1FFFF;
            }
            if (tid < NPB) {
                int gn = b * NPB + tid;
                if (gn < N_NODES) {
                    off[gn] = base + offL[tid];
                    deg[gn] = cnt[tid];
                }
            }
            __syncthreads();                       // before next bucket reuses cnt
        }
    }
}

// ================================================================ fused aggregation + GEMM + bias + relu
// 16 nodes per block (one wave each). Guarded 16-edge loop: no serial tail path,
// no shfl index broadcast (quarter reads edge_src directly; 16 lanes same addr).
// agg goes through 2.3 KB LDS into one 16x16 M-tile; x-half + Wb read straight
// from global into MFMA fragments. Output written directly.
__global__ __launch_bounds__(1024, 8) void agg_out_kernel(
    const unsigned short* __restrict__ ab, const int* __restrict__ edge_src,
    const int* __restrict__ off, const int* __restrict__ deg,
    const float* __restrict__ adj_norm, const unsigned short* __restrict__ Wb,
    const float* __restrict__ root_b, float* __restrict__ out)
{
    __shared__ unsigned short a_sh[16 * ASTRIDE];
    const int tid  = threadIdx.x;
    const int wv   = tid >> 6;                    // 0..15: node within block
    const int lane = tid & 63;
    const int q    = lane >> 4, sub = lane & 15;
    const int n0   = blockIdx.x * 16;             // 6250 * 16 == 100000 exactly
    const int n    = n0 + wv;

    const int s  = off[n];
    const int dg = deg[n];
    const unsigned short* __restrict__ xh = ab + sub * 4;

    float a0 = 0.f, a1 = 0.f, a2 = 0.f, a3 = 0.f;
    for (int e0 = 0; e0 < dg; e0 += 16) {         // every iter: predicated 16-edge step
        int e = e0 + q;
        bool k0 = e < dg, k1 = e + 4 < dg, k2 = e + 8 < dg, k3 = e + 12 < dg;
        int i0 = k0 ? edge_src[s + e]      : 0;
        int i1 = k1 ? edge_src[s + e + 4]  : 0;
        int i2 = k2 ? edge_src[s + e + 8]  : 0;
        int i3 = k3 ? edge_src[s + e + 12] : 0;
        uint2 u0 = *reinterpret_cast<const uint2*>(xh + (size_t)i0 * XROW);
        uint2 u1 = *reinterpret_cast<const uint2*>(xh + (size_t)i1 * XROW);
        uint2 u2 = *reinterpret_cast<const uint2*>(xh + (size_t)i2 * XROW);
        uint2 u3 = *reinterpret_cast<const uint2*>(xh + (size_t)i3 * XROW);
        if (!k0) { u0.x = 0u; u0.y = 0u; }
        if (!k1) { u1.x = 0u; u1.y = 0u; }
        if (!k2) { u2.x = 0u; u2.y = 0u; }
        if (!k3) { u3.x = 0u; u3.y = 0u; }
        a0 += __uint_as_float(u0.x << 16) + __uint_as_float(u1.x << 16)
            + __uint_as_float(u2.x << 16) + __uint_as_float(u3.x << 16);
        a1 += __uint_as_float(u0.x & 0xffff0000u) + __uint_as_float(u1.x & 0xffff0000u)
            + __uint_as_float(u2.x & 0xffff0000u) + __uint_as_float(u3.x & 0xffff0000u);
        a2 += __uint_as_float(u0.y << 16) + __uint_as_float(u1.y << 16)
            + __uint_as_float(u2.y << 16) + __uint_as_float(u3.y << 16);
        a3 += __uint_as_float(u0.y & 0xffff0000u) + __uint_as_float(u1.y & 0xffff0000u)
            + __uint_as_float(u2.y & 0xffff0000u) + __uint_as_float(u3.y & 0xffff0000u);
    }

    a0 += __shfl_xor(a0, 16, 64); a0 += __shfl_xor(a0, 32, 64);
    a1 += __shfl_xor(a1, 16, 64); a1 += __shfl_xor(a1, 32, 64);
    a2 += __shfl_xor(a2, 16, 64); a2 += __shfl_xor(a2, 32, 64);
    a3 += __shfl_xor(a3, 16, 64); a3 += __shfl_xor(a3, 32, 64);

    if (q == 0) {
        float inv = 1.0f / adj_norm[n];
        uint2 p;
        p.x = (unsigned)f2bf(a0 * inv) | ((unsigned)f2bf(a1 * inv) << 16);
        p.y = (unsigned)f2bf(a2 * inv) | ((unsigned)f2bf(a3 * inv) << 16);
        *reinterpret_cast<uint2*>(a_sh + wv * ASTRIDE + sub * 4) = p;
    }
    __syncthreads();

    if (wv < 4) {                                 // wave wv handles N-tile t = wv
        f32x4 c = {0.f, 0.f, 0.f, 0.f};
        #pragma unroll
        for (int kk = 0; kk < 4; ++kk) {          // K = [agg(0:64) | x(64:128)]
            bf16x8 af;
            if (kk < 2)
                af = *reinterpret_cast<const bf16x8*>(a_sh + sub * ASTRIDE + q * 8 + kk * 32);
            else
                af = *reinterpret_cast<const bf16x8*>(ab + (size_t)(n0 + sub) * XROW
                                                      + q * 8 + (kk - 2) * 32);
            bf16x8 bf = *reinterpret_cast<const bf16x8*>(Wb + (wv * 16 + sub) * WROW
                                                         + q * 8 + kk * 32);
            c = __builtin_amdgcn_mfma_f32_16x16x32_bf16(af, bf, c, 0, 0, 0);
        }
        int j = wv * 16 + sub;
        float bias = root_b[j];
        #pragma unroll
        for (int r = 0; r < 4; ++r) {
            int node = n0 + q * 4 + r;
            out[(size_t)node * D + j] = fmaxf(c[r] + bias, 0.0f);
        }
    }
}

// ================================================================ launch
extern "C" void kernel_launch(void* const* d_in, const int* in_sizes, int n_in,
                              void* d_out, int out_size, void* d_ws, size_t ws_size,
                              hipStream_t stream)
{
    const float* x        = (const float*)d_in[0];
    const int*   row      = (const int*)d_in[1];
    const int*   col      = (const int*)d_in[2];
    const float* adj_norm = (const float*)d_in[4];
    const float* root_W   = (const float*)d_in[5];
    const float* root_b   = (const float*)d_in[6];
    const float* rel_W    = (const float*)d_in[7];
    float* out = (float*)d_out;

    char* ws = (char*)d_ws;
    int* bar        = (int*)ws;  ws += 16;                                        // {cnt, gen, pad}
    int* bucketTot  = (int*)ws;  ws += ((size_t)NBUCK * 4 + 15) / 16 * 16;
    int* bucketBase = (int*)ws;  ws += ((size_t)NBUCK * 4 + 15) / 16 * 16;
    int* bucketCur  = (int*)ws;  ws += ((size_t)NBUCK * 4 + 15) / 16 * 16;
    unsigned short* ab = (unsigned short*)ws;  ws += (size_t)N_NODES * XROW * 2;  // 12.8 MB
    unsigned short* Wb = (unsigned short*)ws;  ws += 64 * WROW * 2;               // 16 KB
    int* off        = (int*)ws;  ws += (size_t)N_NODES * 4;
    int* deg        = (int*)ws;  ws += (size_t)N_NODES * 4;
    int* edges      = (int*)ws;  ws += (size_t)N_EDGES * 4;                       // 6.4 MB
    int* edge_src   = (int*)ws;                                                   // 6.4 MB

    // zero barrier state + bucket totals (bar and bucketTot are contiguous)
    hipMemsetAsync(bar, 0, 16 + (size_t)NBUCK * 4, stream);

    pre_kernel<<<NCHUNK, 1024, 0, stream>>>(x, rel_W, root_W, row, col, ab, Wb,
                                            bar, bucketTot, bucketBase, bucketCur,
                                            edges, edge_src, off, deg);

    agg_out_kernel<<<N_NODES / 16, 1024, 0, stream>>>(ab, edge_src, off, deg,
                                                      adj_norm, Wb, root_b, out);
}